// Round 6
// baseline (238.131 us; speedup 1.0000x reference)
//
#include <hip/hip_runtime.h>
#include <hip/hip_bf16.h>

#define NN 10000
#define EE 640000
#define CIN 128
#define COUT 128
#define HH 256
#define SLOT 160
#define BN_EPS 1e-5f
#define XPITCH 136   // shorts per staged x row (+8 pad)
#define HPITCH 264   // shorts per hbuf row (+8 pad)

typedef __attribute__((ext_vector_type(8))) short short8x;
typedef __attribute__((ext_vector_type(4))) float floatx4;

// Static device scratch (re-initialized every launch; graph-capture safe).
__device__ float          g_A[NN * HH];            // fp32 node term A = xn@(W1t-W1b)+b1
__device__ unsigned short g_Bb[NN * HH];           // bf16 node term B = xn@W1b
__device__ int            g_cnt[NN];               // per-node edge count
__device__ int            g_slots[NN * SLOT + 64]; // src ids, slotted by dst
__device__ unsigned short g_W2f[8 * 8 * 64 * 8];   // W2 bf16, MFMA B-frag order
__device__ unsigned short g_W1f[32 * 4 * 64 * 8];  // [W1t-W1b | W1b] bf16, B-frag order

__device__ __forceinline__ unsigned short f2bf(float f) {
    unsigned u = __float_as_uint(f);
    u += 0x7fffu + ((u >> 16) & 1u);   // RNE
    return (unsigned short)(u >> 16);
}
__device__ __forceinline__ float bf2f(unsigned short h) {
    return __uint_as_float(((unsigned)h) << 16);
}
// Packed f32x2 -> bf16x2 (v_cvt_pk_bf16_f32 on gfx950).
__device__ __forceinline__ unsigned pkbf(float a, float b) {
    __hip_bfloat162 t = __float22bfloat162_rn(make_float2(a, b));
    union { __hip_bfloat162 h; unsigned u; } cv; cv.h = t;
    return cv.u;
}

// Merged prep: zero g_cnt, swizzle W2, fold+swizzle W1, zero out.
__global__ void prep_kernel(const float* __restrict__ W1, const float* __restrict__ W2,
                            float* __restrict__ out) {
    const int b = blockIdx.x, tid = threadIdx.x;
    if (b < 40) {
        int i = b * 256 + tid;
        if (i < NN) g_cnt[i] = 0;
        return;
    }
    if (b < 56) {
        int idx = (b - 40) * 256 + tid;        // 0..4095
        int lane = idx & 63;
        int quad = lane >> 4, m = lane & 15;
        int t = idx >> 9, k0 = (idx >> 6) & 7;
        unsigned short frag[8];
        #pragma unroll
        for (int j = 0; j < 8; j++)
            frag[j] = f2bf(W2[(k0 * 32 + quad * 8 + j) * COUT + t * 16 + m]);
        *(short8x*)(g_W2f + (size_t)idx * 8) = *(short8x*)frag;
        return;
    }
    if (b < 88) {
        int idx = (b - 56) * 256 + tid;        // 0..8191
        int lane = idx & 63;
        int quad = lane >> 4, m = lane & 15;
        int t = idx >> 8, k0 = (idx >> 6) & 3;
        int c = t * 16 + m;                    // global col 0..511
        unsigned short frag[8];
        #pragma unroll
        for (int j = 0; j < 8; j++) {
            int k = k0 * 32 + quad * 8 + j;
            float v = (c < 256) ? (W1[k * HH + c] - W1[(k + CIN) * HH + c])
                                : W1[(k + CIN) * HH + (c - 256)];
            frag[j] = f2bf(v);
        }
        *(short8x*)(g_W1f + (size_t)idx * 8) = *(short8x*)frag;
        return;
    }
    // zero out: 1250 blocks x 256 float4 = 1.28M floats
    int idx = (b - 88) * 256 + tid;
    if (idx < NN * COUT / 4)
        ((float4*)out)[idx] = make_float4(0.f, 0.f, 0.f, 0.f);
}

// Stage 1 via MFMA: [A|B] = (xh+xl) @ W1f, 32 nodes/block.
__global__ __launch_bounds__(256) void stage1_kernel(
    const float* __restrict__ x, const float* __restrict__ gamma,
    const float* __restrict__ beta, const float* __restrict__ mean,
    const float* __restrict__ var, const float* __restrict__ b1)
{
    __shared__ unsigned short xh[32 * XPITCH];
    __shared__ unsigned short xl[32 * XPITCH];
    __shared__ float s_lds[CIN], t_lds[CIN];
    const int tid = threadIdx.x;
    const int w = tid >> 6, lane = tid & 63;
    const int m = lane & 15, quad = lane >> 4;
    if (tid < CIN) {
        float s = gamma[tid] * rsqrtf(var[tid] + BN_EPS);
        s_lds[tid] = s;
        t_lds[tid] = beta[tid] - mean[tid] * s;
    }
    __syncthreads();
    const int mbase = blockIdx.x * 32;
    #pragma unroll
    for (int it = 0; it < 4; it++) {
        int slot = it * 256 + tid;
        int n = slot >> 5;
        int k = (slot & 31) * 4;
        int node = mbase + n;
        float4 v = make_float4(0.f, 0.f, 0.f, 0.f);
        if (node < NN) v = *(const float4*)(x + (size_t)node * CIN + k);
        float f[4] = {v.x, v.y, v.z, v.w};
        ushort4 uh, ul;
        unsigned short hb;
        float fn;
        fn = f[0] * s_lds[k + 0] + t_lds[k + 0]; hb = f2bf(fn); uh.x = hb; ul.x = f2bf(fn - bf2f(hb));
        fn = f[1] * s_lds[k + 1] + t_lds[k + 1]; hb = f2bf(fn); uh.y = hb; ul.y = f2bf(fn - bf2f(hb));
        fn = f[2] * s_lds[k + 2] + t_lds[k + 2]; hb = f2bf(fn); uh.z = hb; ul.z = f2bf(fn - bf2f(hb));
        fn = f[3] * s_lds[k + 3] + t_lds[k + 3]; hb = f2bf(fn); uh.w = hb; ul.w = f2bf(fn - bf2f(hb));
        *(ushort4*)(xh + n * XPITCH + k) = uh;
        *(ushort4*)(xl + n * XPITCH + k) = ul;
    }
    __syncthreads();

    floatx4 acc[2][8];
    #pragma unroll
    for (int mt = 0; mt < 2; mt++)
        #pragma unroll
        for (int nt = 0; nt < 8; nt++)
            acc[mt][nt] = (floatx4){0.f, 0.f, 0.f, 0.f};

    #pragma unroll
    for (int k0 = 0; k0 < 4; k0++) {
        short8x wf[8];
        #pragma unroll
        for (int nt = 0; nt < 8; nt++) {
            int t = w * 8 + nt;
            wf[nt] = *(const short8x*)(g_W1f + (size_t)((t * 4 + k0) * 64 + lane) * 8);
        }
        #pragma unroll
        for (int mt = 0; mt < 2; mt++) {
            const unsigned short* rp = xh + (mt * 16 + m) * XPITCH + k0 * 32 + quad * 8;
            const unsigned short* lp = xl + (mt * 16 + m) * XPITCH + k0 * 32 + quad * 8;
            short8x ah = *(const short8x*)rp;
            short8x al = *(const short8x*)lp;
            #pragma unroll
            for (int nt = 0; nt < 8; nt++) {
                acc[mt][nt] = __builtin_amdgcn_mfma_f32_16x16x32_bf16(al, wf[nt], acc[mt][nt], 0, 0, 0);
                acc[mt][nt] = __builtin_amdgcn_mfma_f32_16x16x32_bf16(ah, wf[nt], acc[mt][nt], 0, 0, 0);
            }
        }
    }
    const int colbase = w * 128;
    #pragma unroll
    for (int mt = 0; mt < 2; mt++) {
        #pragma unroll
        for (int nt = 0; nt < 8; nt++) {
            int col = colbase + nt * 16 + m;
            #pragma unroll
            for (int j = 0; j < 4; j++) {
                int node = mbase + mt * 16 + quad * 4 + j;
                if (node < NN) {
                    float v = acc[mt][nt][j];
                    if (col < 256) g_A[(size_t)node * HH + col] = v + b1[col];
                    else           g_Bb[(size_t)node * HH + (col - 256)] = f2bf(v);
                }
            }
        }
    }
}

// Single-pass slot scatter, 4 edges/thread (int4 loads).
__global__ void scatter_kernel(const int* __restrict__ ei) {
    int t = blockIdx.x * 256 + threadIdx.x;
    int e = t * 4;
    if (e < EE) {
        int4 s4 = *(const int4*)(ei + e);
        int4 d4 = *(const int4*)(ei + EE + e);
        int p;
        p = atomicAdd(&g_cnt[d4.x], 1); if (p < SLOT) g_slots[d4.x * SLOT + p] = s4.x;
        p = atomicAdd(&g_cnt[d4.y], 1); if (p < SLOT) g_slots[d4.y * SLOT + p] = s4.y;
        p = atomicAdd(&g_cnt[d4.z], 1); if (p < SLOT) g_slots[d4.z * SLOT + p] = s4.z;
        p = atomicAdd(&g_cnt[d4.w], 1); if (p < SLOT) g_slots[d4.w * SLOT + p] = s4.w;
    }
}

// Main kernel: streaming 32-edge periods across 4 nodes/block with atomicMax
// output (relu(max+b2) == max(relu(.+b2)), all values >= 0 so unsigned-bit
// atomicMax over zero-initialized out is the segment max; deg==0 stays 0).
// Double-buffered hbuf -> ONE barrier per period; cross-node gather prefetch.
__global__ __launch_bounds__(256) void edge_kernel(const float* __restrict__ b2,
                                                   float* __restrict__ out)
{
    __shared__ unsigned short hbuf[2][32 * HPITCH];   // 2 x 16.9 KB
    const int tid = threadIdx.x;
    const int w = tid >> 6, lane = tid & 63;
    const int m = lane & 15, quad = lane >> 4;
    const unsigned laneoff = (unsigned)lane << 3;     // lane*8 bytes

    short8x bfrag[2][8];
    #pragma unroll
    for (int nt = 0; nt < 2; nt++)
        #pragma unroll
        for (int k0 = 0; k0 < 8; k0++)
            bfrag[nt][k0] = *(const short8x*)(g_W2f +
                (size_t)(((w * 2 + nt) * 8 + k0) * 64 + lane) * 8);
    const float b2v0 = b2[(w * 2 + 0) * 16 + m];
    const float b2v1 = b2[(w * 2 + 1) * 16 + m];

    const int n0 = blockIdx.x * 4;
    const int n1 = (n0 + 4 < NN) ? n0 + 4 : NN;

    // Find first active (node, tb=0).
    int node = n0, tb = 0, deg = 0;
    bool have = false;
    while (node < n1) {
        int d = g_cnt[node]; if (d > SLOT) d = SLOT;
        if (d > 0) { deg = d; have = true; break; }
        node++;
    }

    uint2 bv[8];
    float4 av;
    if (have) {
        #pragma unroll
        for (int q = 0; q < 8; q++) {
            int r = w * 8 + q;                         // row within period
            int s = g_slots[node * SLOT + tb + r];     // wave-uniform scalar load
            s = (tb + r < deg) ? s : 0;
            bv[q] = *(const uint2*)((const char*)g_Bb + (((unsigned)s << 9) | laneoff));
        }
        av = *(const float4*)(g_A + (size_t)node * HH + lane * 4);
    }

    int buf = 0;
    while (have) {
        // Convert current period's gathers -> hbuf[buf] (consumes bv/av).
        #pragma unroll
        for (int q = 0; q < 8; q++) {
            int r = w * 8 + q;
            uint2 b = bv[q];
            float f0 = __uint_as_float(b.x << 16);
            float f1 = __uint_as_float(b.x & 0xffff0000u);
            float f2 = __uint_as_float(b.y << 16);
            float f3 = __uint_as_float(b.y & 0xffff0000u);
            float h0 = fmaxf(av.x + f0, 0.f);
            float h1 = fmaxf(av.y + f1, 0.f);
            float h2 = fmaxf(av.z + f2, 0.f);
            float h3 = fmaxf(av.w + f3, 0.f);
            uint2 hv;
            hv.x = pkbf(h0, h1);
            hv.y = pkbf(h2, h3);
            *(uint2*)(hbuf[buf] + r * HPITCH + lane * 4) = hv;
        }
        // Save current period identity, then advance (block-uniform).
        const int cn = node, ctb = tb, cdeg = deg;
        tb += 32;
        bool nhave = (tb < deg);
        if (!nhave) {
            for (node = node + 1; node < n1; node++) {
                int d = g_cnt[node]; if (d > SLOT) d = SLOT;
                if (d > 0) { deg = d; tb = 0; nhave = true; break; }
            }
        }
        __syncthreads();   // hbuf[buf] fully written; prior reads of hbuf[buf] long done
        // Prefetch next period's gathers into bv/av (fly during MFMA below).
        if (nhave) {
            #pragma unroll
            for (int q = 0; q < 8; q++) {
                int r = w * 8 + q;
                int s = g_slots[node * SLOT + tb + r];
                s = (tb + r < deg) ? s : 0;
                bv[q] = *(const uint2*)((const char*)g_Bb + (((unsigned)s << 9) | laneoff));
            }
            av = *(const float4*)(g_A + (size_t)node * HH + lane * 4);
        }
        // MFMA on current period; merge mt tiles before flushing.
        float mx0 = -INFINITY, mx1 = -INFINITY;
        #pragma unroll
        for (int mt = 0; mt < 2; mt++) {
            if (ctb + mt * 16 < cdeg) {               // uniform tile-valid check
                const unsigned short* ha = hbuf[buf] + (mt * 16 + m) * HPITCH + quad * 8;
                floatx4 acc0 = {0.f, 0.f, 0.f, 0.f};
                floatx4 acc1 = {0.f, 0.f, 0.f, 0.f};
                #pragma unroll
                for (int k0 = 0; k0 < 8; k0++) {
                    short8x af = *(const short8x*)(ha + k0 * 32);
                    acc0 = __builtin_amdgcn_mfma_f32_16x16x32_bf16(af, bfrag[0][k0], acc0, 0, 0, 0);
                    acc1 = __builtin_amdgcn_mfma_f32_16x16x32_bf16(af, bfrag[1][k0], acc1, 0, 0, 0);
                }
                const int rowbase = ctb + mt * 16 + quad * 4;
                if (rowbase + 4 <= cdeg) {
                    mx0 = fmaxf(mx0, fmaxf(fmaxf(acc0[0], acc0[1]), fmaxf(acc0[2], acc0[3])));
                    mx1 = fmaxf(mx1, fmaxf(fmaxf(acc1[0], acc1[1]), fmaxf(acc1[2], acc1[3])));
                } else {
                    #pragma unroll
                    for (int j = 0; j < 4; j++) {
                        if (rowbase + j < cdeg) {
                            mx0 = fmaxf(mx0, acc0[j]);
                            mx1 = fmaxf(mx1, acc1[j]);
                        }
                    }
                }
            }
        }
        mx0 = fmaxf(mx0, __shfl_xor(mx0, 16));
        mx0 = fmaxf(mx0, __shfl_xor(mx0, 32));
        mx1 = fmaxf(mx1, __shfl_xor(mx1, 16));
        mx1 = fmaxf(mx1, __shfl_xor(mx1, 32));
        if (quad == 0) {
            float v0 = fmaxf(mx0 + b2v0, 0.f);        // -inf -> 0: harmless
            float v1 = fmaxf(mx1 + b2v1, 0.f);
            unsigned* o = (unsigned*)(out + (size_t)cn * COUT);
            atomicMax(o + (w * 2 + 0) * 16 + m, __float_as_uint(v0));
            atomicMax(o + (w * 2 + 1) * 16 + m, __float_as_uint(v1));
        }
        have = nhave;
        buf ^= 1;
    }
}

extern "C" void kernel_launch(void* const* d_in, const int* in_sizes, int n_in,
                              void* d_out, int out_size, void* d_ws, size_t ws_size,
                              hipStream_t stream) {
    const float* x      = (const float*)d_in[0];
    const int*   ei     = (const int*)d_in[1];
    const float* gamma  = (const float*)d_in[2];
    const float* beta   = (const float*)d_in[3];
    const float* mean   = (const float*)d_in[4];
    const float* var    = (const float*)d_in[5];
    const float* W1     = (const float*)d_in[6];
    const float* b1     = (const float*)d_in[7];
    const float* W2     = (const float*)d_in[8];
    const float* b2     = (const float*)d_in[9];
    float* out = (float*)d_out;
    (void)d_ws; (void)ws_size;

    prep_kernel<<<1338, 256, 0, stream>>>(W1, W2, out);
    stage1_kernel<<<(NN + 31) / 32, 256, 0, stream>>>(x, gamma, beta, mean, var, b1);
    scatter_kernel<<<(EE / 4 + 255) / 256, 256, 0, stream>>>(ei);
    edge_kernel<<<NN / 4, 256, 0, stream>>>(b2, out);
}

// Round 7
// 217.896 us; speedup vs baseline: 1.0929x; 1.0929x over previous
//
#include <hip/hip_runtime.h>
#include <hip/hip_bf16.h>

#define NN 10000
#define EE 640000
#define CIN 128
#define COUT 128
#define HH 256
#define SLOT 160
#define BN_EPS 1e-5f
#define XPITCH 136   // shorts per staged x row (+8 pad)
#define HPITCH 264   // shorts per hbuf row (+8 pad)

typedef __attribute__((ext_vector_type(8))) short short8x;
typedef __attribute__((ext_vector_type(4))) float floatx4;

// Static device scratch (re-initialized every launch; graph-capture safe).
__device__ float          g_A[NN * HH];            // fp32 node term A = xn@(W1t-W1b)+b1
__device__ unsigned short g_Bb[NN * HH];           // bf16 node term B = xn@W1b
__device__ int            g_cnt[NN];               // per-node edge count
__device__ int            g_slots[NN * SLOT + 64]; // src ids, slotted by dst
__device__ unsigned short g_W2f[8 * 8 * 64 * 8];   // W2 bf16, MFMA B-frag order
__device__ unsigned short g_W1f[32 * 4 * 64 * 8];  // [W1t-W1b | W1b] bf16, B-frag order

__device__ __forceinline__ unsigned short f2bf(float f) {
    unsigned u = __float_as_uint(f);
    u += 0x7fffu + ((u >> 16) & 1u);   // RNE
    return (unsigned short)(u >> 16);
}
__device__ __forceinline__ float bf2f(unsigned short h) {
    return __uint_as_float(((unsigned)h) << 16);
}
// Packed f32x2 -> bf16x2 (v_cvt_pk_bf16_f32 on gfx950).
__device__ __forceinline__ unsigned pkbf(float a, float b) {
    __hip_bfloat162 t = __float22bfloat162_rn(make_float2(a, b));
    union { __hip_bfloat162 h; unsigned u; } cv; cv.h = t;
    return cv.u;
}

// Merged prep: zero g_cnt, swizzle W2, fold+swizzle W1.
__global__ void prep_kernel(const float* __restrict__ W1, const float* __restrict__ W2) {
    const int b = blockIdx.x, tid = threadIdx.x;
    if (b < 40) {
        int i = b * 256 + tid;
        if (i < NN) g_cnt[i] = 0;
        return;
    }
    if (b < 56) {
        int idx = (b - 40) * 256 + tid;        // 0..4095
        int lane = idx & 63;
        int quad = lane >> 4, m = lane & 15;
        int t = idx >> 9, k0 = (idx >> 6) & 7;
        unsigned short frag[8];
        #pragma unroll
        for (int j = 0; j < 8; j++)
            frag[j] = f2bf(W2[(k0 * 32 + quad * 8 + j) * COUT + t * 16 + m]);
        *(short8x*)(g_W2f + (size_t)idx * 8) = *(short8x*)frag;
        return;
    }
    int idx = (b - 56) * 256 + tid;            // 0..8191
    int lane = idx & 63;
    int quad = lane >> 4, m = lane & 15;
    int t = idx >> 8, k0 = (idx >> 6) & 3;
    int c = t * 16 + m;                        // global col 0..511
    unsigned short frag[8];
    #pragma unroll
    for (int j = 0; j < 8; j++) {
        int k = k0 * 32 + quad * 8 + j;
        float v = (c < 256) ? (W1[k * HH + c] - W1[(k + CIN) * HH + c])
                            : W1[(k + CIN) * HH + (c - 256)];
        frag[j] = f2bf(v);
    }
    *(short8x*)(g_W1f + (size_t)idx * 8) = *(short8x*)frag;
}

// Stage 1 via MFMA: [A|B] = (xh+xl) @ W1f, 32 nodes/block.
__global__ __launch_bounds__(256) void stage1_kernel(
    const float* __restrict__ x, const float* __restrict__ gamma,
    const float* __restrict__ beta, const float* __restrict__ mean,
    const float* __restrict__ var, const float* __restrict__ b1)
{
    __shared__ unsigned short xh[32 * XPITCH];
    __shared__ unsigned short xl[32 * XPITCH];
    __shared__ float s_lds[CIN], t_lds[CIN];
    const int tid = threadIdx.x;
    const int w = tid >> 6, lane = tid & 63;
    const int m = lane & 15, quad = lane >> 4;
    if (tid < CIN) {
        float s = gamma[tid] * rsqrtf(var[tid] + BN_EPS);
        s_lds[tid] = s;
        t_lds[tid] = beta[tid] - mean[tid] * s;
    }
    __syncthreads();
    const int mbase = blockIdx.x * 32;
    #pragma unroll
    for (int it = 0; it < 4; it++) {
        int slot = it * 256 + tid;
        int n = slot >> 5;
        int k = (slot & 31) * 4;
        int node = mbase + n;
        float4 v = make_float4(0.f, 0.f, 0.f, 0.f);
        if (node < NN) v = *(const float4*)(x + (size_t)node * CIN + k);
        float f[4] = {v.x, v.y, v.z, v.w};
        ushort4 uh, ul;
        unsigned short hb;
        float fn;
        fn = f[0] * s_lds[k + 0] + t_lds[k + 0]; hb = f2bf(fn); uh.x = hb; ul.x = f2bf(fn - bf2f(hb));
        fn = f[1] * s_lds[k + 1] + t_lds[k + 1]; hb = f2bf(fn); uh.y = hb; ul.y = f2bf(fn - bf2f(hb));
        fn = f[2] * s_lds[k + 2] + t_lds[k + 2]; hb = f2bf(fn); uh.z = hb; ul.z = f2bf(fn - bf2f(hb));
        fn = f[3] * s_lds[k + 3] + t_lds[k + 3]; hb = f2bf(fn); uh.w = hb; ul.w = f2bf(fn - bf2f(hb));
        *(ushort4*)(xh + n * XPITCH + k) = uh;
        *(ushort4*)(xl + n * XPITCH + k) = ul;
    }
    __syncthreads();

    floatx4 acc[2][8];
    #pragma unroll
    for (int mt = 0; mt < 2; mt++)
        #pragma unroll
        for (int nt = 0; nt < 8; nt++)
            acc[mt][nt] = (floatx4){0.f, 0.f, 0.f, 0.f};

    #pragma unroll
    for (int k0 = 0; k0 < 4; k0++) {
        short8x wf[8];
        #pragma unroll
        for (int nt = 0; nt < 8; nt++) {
            int t = w * 8 + nt;
            wf[nt] = *(const short8x*)(g_W1f + (size_t)((t * 4 + k0) * 64 + lane) * 8);
        }
        #pragma unroll
        for (int mt = 0; mt < 2; mt++) {
            const unsigned short* rp = xh + (mt * 16 + m) * XPITCH + k0 * 32 + quad * 8;
            const unsigned short* lp = xl + (mt * 16 + m) * XPITCH + k0 * 32 + quad * 8;
            short8x ah = *(const short8x*)rp;
            short8x al = *(const short8x*)lp;
            #pragma unroll
            for (int nt = 0; nt < 8; nt++) {
                acc[mt][nt] = __builtin_amdgcn_mfma_f32_16x16x32_bf16(al, wf[nt], acc[mt][nt], 0, 0, 0);
                acc[mt][nt] = __builtin_amdgcn_mfma_f32_16x16x32_bf16(ah, wf[nt], acc[mt][nt], 0, 0, 0);
            }
        }
    }
    const int colbase = w * 128;
    #pragma unroll
    for (int mt = 0; mt < 2; mt++) {
        #pragma unroll
        for (int nt = 0; nt < 8; nt++) {
            int col = colbase + nt * 16 + m;
            #pragma unroll
            for (int j = 0; j < 4; j++) {
                int node = mbase + mt * 16 + quad * 4 + j;
                if (node < NN) {
                    float v = acc[mt][nt][j];
                    if (col < 256) g_A[(size_t)node * HH + col] = v + b1[col];
                    else           g_Bb[(size_t)node * HH + (col - 256)] = f2bf(v);
                }
            }
        }
    }
}

// Single-pass slot scatter, 4 edges/thread (int4 loads).
__global__ void scatter_kernel(const int* __restrict__ ei) {
    int t = blockIdx.x * 256 + threadIdx.x;
    int e = t * 4;
    if (e < EE) {
        int4 s4 = *(const int4*)(ei + e);
        int4 d4 = *(const int4*)(ei + EE + e);
        int p;
        p = atomicAdd(&g_cnt[d4.x], 1); if (p < SLOT) g_slots[d4.x * SLOT + p] = s4.x;
        p = atomicAdd(&g_cnt[d4.y], 1); if (p < SLOT) g_slots[d4.y * SLOT + p] = s4.y;
        p = atomicAdd(&g_cnt[d4.z], 1); if (p < SLOT) g_slots[d4.z * SLOT + p] = s4.z;
        p = atomicAdd(&g_cnt[d4.w], 1); if (p < SLOT) g_slots[d4.w * SLOT + p] = s4.w;
    }
}

// Main kernel: 512 threads = 8 waves; wave w owns 16 output channels.
// 4 nodes/block sequentially, 32-edge periods, 2-barrier structure,
// register W2 frags (32 VGPR/wave), gather prefetch overlapping MFMA.
__global__ __launch_bounds__(512) void edge_kernel(const float* __restrict__ b2,
                                                   float* __restrict__ out)
{
    __shared__ unsigned short hbuf[32 * HPITCH];   // 16.9 KB
    __shared__ int sbuf[SLOT];
    const int tid = threadIdx.x;
    const int w = tid >> 6, lane = tid & 63;
    const int m = lane & 15, quad = lane >> 4;
    const unsigned laneoff = (unsigned)lane << 3;  // lane*8 bytes

    // Wave w's 16 channels: B-frags for n-tile t=w (32 VGPRs).
    short8x bfrag[8];
    #pragma unroll
    for (int k0 = 0; k0 < 8; k0++)
        bfrag[k0] = *(const short8x*)(g_W2f + (size_t)((w * 8 + k0) * 64 + lane) * 8);
    const float b2v = b2[w * 16 + m];

    for (int g = 0; g < 4; g++) {
        const int node = blockIdx.x * 4 + g;
        int deg = g_cnt[node]; if (deg > SLOT) deg = SLOT;
        const float4 av = *(const float4*)(g_A + (size_t)node * HH + lane * 4);
        __syncthreads();                  // prev node fully done with sbuf/hbuf
        if (tid < deg) sbuf[tid] = g_slots[node * SLOT + tid];
        __syncthreads();                  // sbuf ready
        float rm = -INFINITY;
        if (deg > 0) {
            const int ntp = (deg + 31) >> 5;
            uint2 bv[4];
            #pragma unroll
            for (int q = 0; q < 4; q++) {   // prefetch period 0; rows w*4..w*4+3
                int er = w * 4 + q;
                int sv = (er < deg) ? sbuf[er] : 0;
                bv[q] = *(const uint2*)((const char*)g_Bb + (((unsigned)sv << 9) | laneoff));
            }
            for (int p = 0; p < ntp; p++) {
                const int tb = p << 5;
                #pragma unroll
                for (int q = 0; q < 4; q++) {
                    int r = w * 4 + q;
                    uint2 b = bv[q];
                    float f0 = __uint_as_float(b.x << 16);
                    float f1 = __uint_as_float(b.x & 0xffff0000u);
                    float f2 = __uint_as_float(b.y << 16);
                    float f3 = __uint_as_float(b.y & 0xffff0000u);
                    float h0 = fmaxf(av.x + f0, 0.f);
                    float h1 = fmaxf(av.y + f1, 0.f);
                    float h2 = fmaxf(av.z + f2, 0.f);
                    float h3 = fmaxf(av.w + f3, 0.f);
                    uint2 hv;
                    hv.x = pkbf(h0, h1);
                    hv.y = pkbf(h2, h3);
                    *(uint2*)(hbuf + r * HPITCH + lane * 4) = hv;
                }
                __syncthreads();          // hbuf(p) ready
                if (p + 1 < ntp) {        // prefetch next period during MFMA
                    #pragma unroll
                    for (int q = 0; q < 4; q++) {
                        int er = tb + 32 + w * 4 + q;
                        int sv = (er < deg) ? sbuf[er] : 0;
                        bv[q] = *(const uint2*)((const char*)g_Bb + (((unsigned)sv << 9) | laneoff));
                    }
                }
                #pragma unroll
                for (int mt = 0; mt < 2; mt++) {
                    if (tb + mt * 16 < deg) {    // block-uniform tile-valid check
                        const unsigned short* ha = hbuf + (mt * 16 + m) * HPITCH + quad * 8;
                        floatx4 acc = {0.f, 0.f, 0.f, 0.f};
                        #pragma unroll
                        for (int k0 = 0; k0 < 8; k0++) {
                            short8x af = *(const short8x*)(ha + k0 * 32);
                            acc = __builtin_amdgcn_mfma_f32_16x16x32_bf16(af, bfrag[k0], acc, 0, 0, 0);
                        }
                        const int rowbase = tb + mt * 16 + quad * 4;
                        if (rowbase + 4 <= deg) {
                            rm = fmaxf(rm, fmaxf(fmaxf(acc[0], acc[1]), fmaxf(acc[2], acc[3])));
                        } else {
                            #pragma unroll
                            for (int j = 0; j < 4; j++)
                                if (rowbase + j < deg) rm = fmaxf(rm, acc[j]);
                        }
                    }
                }
                __syncthreads();          // all waves done reading hbuf(p)
            }
        }
        // Cross-quad reduction once per node; block owns node -> plain store.
        rm = fmaxf(rm, __shfl_xor(rm, 16));
        rm = fmaxf(rm, __shfl_xor(rm, 32));
        if (quad == 0) {
            float v = (deg > 0) ? fmaxf(rm + b2v, 0.f) : 0.f;
            out[(size_t)node * COUT + w * 16 + m] = v;
        }
    }
}

extern "C" void kernel_launch(void* const* d_in, const int* in_sizes, int n_in,
                              void* d_out, int out_size, void* d_ws, size_t ws_size,
                              hipStream_t stream) {
    const float* x      = (const float*)d_in[0];
    const int*   ei     = (const int*)d_in[1];
    const float* gamma  = (const float*)d_in[2];
    const float* beta   = (const float*)d_in[3];
    const float* mean   = (const float*)d_in[4];
    const float* var    = (const float*)d_in[5];
    const float* W1     = (const float*)d_in[6];
    const float* b1     = (const float*)d_in[7];
    const float* W2     = (const float*)d_in[8];
    const float* b2     = (const float*)d_in[9];
    float* out = (float*)d_out;
    (void)d_ws; (void)ws_size;

    prep_kernel<<<88, 256, 0, stream>>>(W1, W2);
    stage1_kernel<<<(NN + 31) / 32, 256, 0, stream>>>(x, gamma, beta, mean, var, b1);
    scatter_kernel<<<(EE / 4 + 255) / 256, 256, 0, stream>>>(ei);
    edge_kernel<<<NN / 4, 512, 0, stream>>>(b2, out);
}